// Round 7
// baseline (507.407 us; speedup 1.0000x reference)
//
#include <hip/hip_runtime.h>
#include <hip/hip_bf16.h>

typedef _Float16 f16x8  __attribute__((ext_vector_type(8)));
typedef _Float16 f16x16 __attribute__((ext_vector_type(16)));
typedef float    f32x16 __attribute__((ext_vector_type(16)));
typedef float    v2f    __attribute__((ext_vector_type(2)));
typedef unsigned u32x4  __attribute__((ext_vector_type(4)));

#define LOG2E 1.442695040888963f

__device__ __forceinline__ unsigned pk16(float a, float b) {
    return __builtin_bit_cast(unsigned, __builtin_amdgcn_cvt_pkrtz(a, b));
}

// Per wave: 64 batch rows; per step: G^T = W_hh'[64x16] @ h^T[16x64] via
// 4x mfma_f32_32x32x16_f16, processed rb-split (only 2 acc tiles live) to fit
// <=128 total regs -> 4 waves/SIMD. Gate rows prescaled by exp2-arg factor
// (i,f,o: -log2e ; g: +2log2e); c kept scaled (c' = 2log2e*c).
// rcp-minimized: 1 rcp per c-update, 0.5 rcp per h-update (pairwise merge).
__global__ __launch_bounds__(256, 4) void lstm_mfma_kernel(
    const float* __restrict__ mobility,  // [B,7]
    const float* __restrict__ controls,  // [B,5]
    const float* __restrict__ W_cc, const float* __restrict__ b_cc,
    const float* __restrict__ W_ih, const float* __restrict__ W_hh,
    const float* __restrict__ b_ih, const float* __restrict__ b_hh,
    const float* __restrict__ W1,  const float* __restrict__ b1,
    const float* __restrict__ W2,  const float* __restrict__ b2,
    const float* __restrict__ W3,  const float* __restrict__ b3,
    float* __restrict__ out, int Btot)
{
    __shared__ float hbuf[256][17];   // stride 17: conflict-free

    const int tid  = threadIdx.x;
    const int lane = tid & 63;
    const int wib  = tid >> 6;
    const int col  = lane & 31;
    const int hi   = lane >> 5;

    const int blockRow0 = blockIdx.x * 256;
    const int r_lo = blockRow0 + wib * 64 + col;
    const int r_hi = r_lo + 32;

    // mobility preload; t-loop is FULLY unrolled so these index statically (regs)
    float mlo[7], mhi[7];
    #pragma unroll
    for (int t = 0; t < 7; ++t) { mlo[t] = mobility[r_lo * 7 + t]; mhi[t] = mobility[r_hi * 7 + t]; }

    // ---- A fragments: W_hh * rowscale -> f16 (8 regs, wave-shared weights) ----
    f16x8 afrag[2];
    #pragma unroll
    for (int gb = 0; gb < 2; ++gb) {
        const float s = (gb == 0) ? -LOG2E : ((col < 16) ? 2.0f * LOG2E : -LOG2E);
        const float* wr = W_hh + (gb * 32 + col) * 16 + hi * 8;
        u32x4 aw = { pk16(s * wr[0], s * wr[1]), pk16(s * wr[2], s * wr[3]),
                     pk16(s * wr[4], s * wr[5]), pk16(s * wr[6], s * wr[7]) };
        afrag[gb] = __builtin_bit_cast(f16x8, aw);
    }

    // ---- bias & W_ih in D-layout, prescaled, PACKED f16 (16 regs total) ----
    f16x16 bias_h[2], wih_h[2];
    #pragma unroll
    for (int gb = 0; gb < 2; ++gb)
        #pragma unroll
        for (int q = 0; q < 4; ++q) {
            const int gu = gb * 32 + 8 * q + 4 * hi;
            const float s = (gu < 32) ? -LOG2E : ((gu < 48) ? 2.0f * LOG2E : -LOG2E);
            #pragma unroll
            for (int e = 0; e < 4; ++e) {
                bias_h[gb][4 * q + e] = (_Float16)(s * (b_ih[gu + e] + b_hh[gu + e]));
                wih_h [gb][4 * q + e] = (_Float16)(s * W_ih[gu + e]);
            }
        }

    float c[2][8];
    #pragma unroll
    for (int rb = 0; rb < 2; ++rb)
        #pragma unroll
        for (int u = 0; u < 8; ++u) c[rb][u] = 0.0f;

    u32x4 bz = { 0u, 0u, 0u, 0u };
    f16x8 bfrag[2];
    bfrag[0] = __builtin_bit_cast(f16x8, bz);
    bfrag[1] = __builtin_bit_cast(f16x8, bz);

    #pragma unroll
    for (int t = 0; t < 7; ++t) {
        #pragma unroll
        for (int rb = 0; rb < 2; ++rb) {   // rb-split: only 2 acc tiles live at once
            const float xt = rb ? mhi[t] : mlo[t];

            f32x16 cin0, cin1;
            #pragma unroll
            for (int r = 0; r < 16; ++r)
                cin0[r] = fmaf(xt, (float)wih_h[0][r], (float)bias_h[0][r]);  // v_fma_mix
            f32x16 a0 = __builtin_amdgcn_mfma_f32_32x32x16_f16(afrag[0], bfrag[rb], cin0, 0, 0, 0);
            #pragma unroll
            for (int r = 0; r < 16; ++r)
                cin1[r] = fmaf(xt, (float)wih_h[1][r], (float)bias_h[1][r]);
            f32x16 a1 = __builtin_amdgcn_mfma_f32_32x32x16_f16(afrag[1], bfrag[rb], cin1, 0, 0, 0);

            float dh[8], nh[8], h[8];
            #pragma unroll
            for (int u = 0; u < 8; ++u) {
                const float ea = __builtin_amdgcn_exp2f(a0[u]);      // e^{-gi}
                const float ef = __builtin_amdgcn_exp2f(a0[u + 8]);  // e^{-gf}
                const float eb = __builtin_amdgcn_exp2f(a1[u]);      // e^{2gg}
                const float eo = __builtin_amdgcn_exp2f(a1[u + 8]);  // e^{-go}
                const float pf   = 1.0f + ef;
                const float pa   = 1.0f + ea;
                const float den1 = fmaf(pa, eb, pa);                  // (1+ea)(eb+1)
                const float D    = den1 * pf;
                const float rD   = __builtin_amdgcn_rcpf(D);
                const float num  = fmaf(eb, 2.0f * LOG2E, -2.0f * LOG2E);
                const float m1   = num * pf;
                const float cn   = fmaf(c[rb][u], den1, m1);
                const float cs   = cn * rD;
                c[rb][u] = cs;
                const float ec   = __builtin_amdgcn_exp2f(cs);        // e^{2c}
                const float ph   = 1.0f + eo;
                dh[u] = fmaf(ph, ec, ph);                             // (1+eo)(ec+1)
                nh[u] = ec - 1.0f;
            }
            #pragma unroll
            for (int u = 0; u < 8; u += 2) {
                const float P  = dh[u] * dh[u + 1];
                const float rP = __builtin_amdgcn_rcpf(P);
                h[u]     = (nh[u]     * dh[u + 1]) * rP;
                h[u + 1] = (nh[u + 1] * dh[u])     * rP;
            }
            unsigned q0 = pk16(h[0], h[1]);
            unsigned q1 = pk16(h[2], h[3]);
            unsigned q2 = pk16(h[4], h[5]);
            unsigned q3 = pk16(h[6], h[7]);
            auto s02 = __builtin_amdgcn_permlane32_swap(q0, q2, false, false);
            auto s13 = __builtin_amdgcn_permlane32_swap(q1, q3, false, false);
            u32x4 bw = { s02[0], s13[0], s02[1], s13[1] };
            bfrag[rb] = __builtin_bit_cast(f16x8, bw);
        }
    }

    // ---- final h straight from bfrag (B layout: lane holds units hi*8+e of col) ----
    #pragma unroll
    for (int rb = 0; rb < 2; ++rb) {
        const int rr = wib * 64 + col + rb * 32;
        #pragma unroll
        for (int e = 0; e < 8; ++e)
            hbuf[rr][hi * 8 + e] = (float)bfrag[rb][e];
    }
    __syncthreads();

    // ---- fc stage: thread tid owns block-local row tid ----
    const int grow = blockRow0 + tid;

    float x19[19];
    #pragma unroll
    for (int k = 0; k < 16; ++k) x19[k] = hbuf[tid][k];

    float ctl[5];
    #pragma unroll
    for (int k = 0; k < 5; ++k) ctl[k] = controls[grow * 5 + k];
    #pragma unroll
    for (int j = 0; j < 3; ++j) {
        float a = b_cc[j];
        #pragma unroll
        for (int k = 0; k < 5; ++k) a = fmaf(ctl[k], W_cc[j * 5 + k], a);
        x19[16 + j] = a;
    }

    // fc1: Linear(19->16); tanh via pairwise-merged rcp
    float d1[16];
    #pragma unroll
    for (int j = 0; j < 16; ++j) {
        float a = b1[j];
        #pragma unroll
        for (int k = 0; k < 19; ++k) a = fmaf(x19[k], W1[j * 19 + k], a);
        d1[j] = __builtin_amdgcn_exp2f((2.0f * LOG2E) * a) + 1.0f;
    }
    v2f t12[8];
    #pragma unroll
    for (int j = 0; j < 16; j += 2) {
        const float rP = __builtin_amdgcn_rcpf(d1[j] * d1[j + 1]);
        t12[j >> 1][0] = fmaf(-2.0f * d1[j + 1], rP, 1.0f);
        t12[j >> 1][1] = fmaf(-2.0f * d1[j],     rP, 1.0f);
    }

    // fc2: Linear(16->16) + tanh (packed fma, pairwise-merged rcp)
    float d2[16];
    #pragma unroll
    for (int j = 0; j < 16; ++j) {
        const v2f* w2row = (const v2f*)(W2 + j * 16);
        v2f a = t12[0] * w2row[0];
        #pragma unroll
        for (int p = 1; p < 8; ++p) a = __builtin_elementwise_fma(t12[p], w2row[p], a);
        d2[j] = __builtin_amdgcn_exp2f((2.0f * LOG2E) * (a.x + a.y + b2[j])) + 1.0f;
    }
    v2f t22[8];
    #pragma unroll
    for (int j = 0; j < 16; j += 2) {
        const float rP = __builtin_amdgcn_rcpf(d2[j] * d2[j + 1]);
        t22[j >> 1][0] = fmaf(-2.0f * d2[j + 1], rP, 1.0f);
        t22[j >> 1][1] = fmaf(-2.0f * d2[j],     rP, 1.0f);
    }

    // fc3: Linear(16->1) + ReLU
    const v2f* w3p = (const v2f*)W3;
    v2f a3 = t22[0] * w3p[0];
    #pragma unroll
    for (int p = 1; p < 8; ++p) a3 = __builtin_elementwise_fma(t22[p], w3p[p], a3);
    const float r = a3.x + a3.y + b3[0];
    if (grow < Btot) out[grow] = fmaxf(r, 0.0f);
}

extern "C" void kernel_launch(void* const* d_in, const int* in_sizes, int n_in,
                              void* d_out, int out_size, void* d_ws, size_t ws_size,
                              hipStream_t stream) {
    const float* mobility = (const float*)d_in[0];
    const float* controls = (const float*)d_in[1];
    // d_in[2] = last : unused by the reference
    const float* W_cc = (const float*)d_in[3];
    const float* b_cc = (const float*)d_in[4];
    const float* W_ih = (const float*)d_in[5];
    const float* W_hh = (const float*)d_in[6];
    const float* b_ih = (const float*)d_in[7];
    const float* b_hh = (const float*)d_in[8];
    const float* W1   = (const float*)d_in[9];
    const float* b1   = (const float*)d_in[10];
    const float* W2   = (const float*)d_in[11];
    const float* b2   = (const float*)d_in[12];
    const float* W3   = (const float*)d_in[13];
    const float* b3   = (const float*)d_in[14];
    float* out = (float*)d_out;

    const int Btot = in_sizes[0] / 7;          // 1048576
    const int grid = (Btot + 255) / 256;       // 256 rows per block (4 waves x 64)

    lstm_mfma_kernel<<<grid, 256, 0, stream>>>(
        mobility, controls, W_cc, b_cc, W_ih, W_hh, b_ih, b_hh,
        W1, b1, W2, b2, W3, b3, out, Btot);
}

// Round 8
// 115.395 us; speedup vs baseline: 4.3971x; 4.3971x over previous
//
#include <hip/hip_runtime.h>
#include <hip/hip_bf16.h>

typedef _Float16 f16x8  __attribute__((ext_vector_type(8)));
typedef _Float16 f16x16 __attribute__((ext_vector_type(16)));
typedef float    f32x16 __attribute__((ext_vector_type(16)));
typedef float    v2f    __attribute__((ext_vector_type(2)));
typedef unsigned u32x4  __attribute__((ext_vector_type(4)));

#define LOG2E 1.442695040888963f

__device__ __forceinline__ unsigned pk16(float a, float b) {
    return __builtin_bit_cast(unsigned, __builtin_amdgcn_cvt_pkrtz(a, b));
}

// Per wave: 64 batch rows; per step: G^T = W_hh'[64x16] @ h^T[16x64] via
// 4x mfma_f32_32x32x16_f16, processed rb-split (only 2 acc tiles live -> 32
// AGPRs). Gate rows prescaled by exp2-arg factor (i,f,o: -log2e; g: +2log2e);
// c kept scaled (c' = 2log2e*c). 1 rcp per c-update, 0.5 per h-update.
// launch_bounds(256,3): unified VGPR+AGPR cap 170 >= ~156 needed -> no spill,
// 3 waves/SIMD (round 7's (256,4) cap 128 caused 2.4 GB of scratch traffic).
__global__ __launch_bounds__(256, 3) void lstm_mfma_kernel(
    const float* __restrict__ mobility,  // [B,7]
    const float* __restrict__ controls,  // [B,5]
    const float* __restrict__ W_cc, const float* __restrict__ b_cc,
    const float* __restrict__ W_ih, const float* __restrict__ W_hh,
    const float* __restrict__ b_ih, const float* __restrict__ b_hh,
    const float* __restrict__ W1,  const float* __restrict__ b1,
    const float* __restrict__ W2,  const float* __restrict__ b2,
    const float* __restrict__ W3,  const float* __restrict__ b3,
    float* __restrict__ out, int Btot)
{
    __shared__ float hbuf[256][17];   // stride 17: conflict-free

    const int tid  = threadIdx.x;
    const int lane = tid & 63;
    const int wib  = tid >> 6;
    const int col  = lane & 31;
    const int hi   = lane >> 5;

    const int blockRow0 = blockIdx.x * 256;
    const int r_lo = blockRow0 + wib * 64 + col;
    const int r_hi = r_lo + 32;

    // mobility preload (rolled t-loop indexes these; r6 showed clean allocation)
    float mlo[7], mhi[7];
    #pragma unroll
    for (int t = 0; t < 7; ++t) { mlo[t] = mobility[r_lo * 7 + t]; mhi[t] = mobility[r_hi * 7 + t]; }

    // ---- A fragments: W_hh * rowscale -> f16 (8 regs, wave-shared weights) ----
    f16x8 afrag[2];
    #pragma unroll
    for (int gb = 0; gb < 2; ++gb) {
        const float s = (gb == 0) ? -LOG2E : ((col < 16) ? 2.0f * LOG2E : -LOG2E);
        const float* wr = W_hh + (gb * 32 + col) * 16 + hi * 8;
        u32x4 aw = { pk16(s * wr[0], s * wr[1]), pk16(s * wr[2], s * wr[3]),
                     pk16(s * wr[4], s * wr[5]), pk16(s * wr[6], s * wr[7]) };
        afrag[gb] = __builtin_bit_cast(f16x8, aw);
    }

    // ---- bias & W_ih in D-layout, prescaled, PACKED f16 (16 regs total) ----
    f16x16 bias_h[2], wih_h[2];
    #pragma unroll
    for (int gb = 0; gb < 2; ++gb)
        #pragma unroll
        for (int q = 0; q < 4; ++q) {
            const int gu = gb * 32 + 8 * q + 4 * hi;
            const float s = (gu < 32) ? -LOG2E : ((gu < 48) ? 2.0f * LOG2E : -LOG2E);
            #pragma unroll
            for (int e = 0; e < 4; ++e) {
                bias_h[gb][4 * q + e] = (_Float16)(s * (b_ih[gu + e] + b_hh[gu + e]));
                wih_h [gb][4 * q + e] = (_Float16)(s * W_ih[gu + e]);
            }
        }

    float c[2][8];
    #pragma unroll
    for (int rb = 0; rb < 2; ++rb)
        #pragma unroll
        for (int u = 0; u < 8; ++u) c[rb][u] = 0.0f;

    u32x4 bz = { 0u, 0u, 0u, 0u };
    f16x8 bfrag[2];
    bfrag[0] = __builtin_bit_cast(f16x8, bz);
    bfrag[1] = __builtin_bit_cast(f16x8, bz);

    #pragma unroll 1   // rolled: round 6 proved clean allocation; unroll ballooned regs
    for (int t = 0; t < 7; ++t) {
        #pragma unroll
        for (int rb = 0; rb < 2; ++rb) {   // rb-split: only 2 acc tiles live at once
            const float xt = rb ? mhi[t] : mlo[t];

            f32x16 cin0, cin1;
            #pragma unroll
            for (int r = 0; r < 16; ++r)
                cin0[r] = fmaf(xt, (float)wih_h[0][r], (float)bias_h[0][r]);  // fma_mix
            f32x16 a0 = __builtin_amdgcn_mfma_f32_32x32x16_f16(afrag[0], bfrag[rb], cin0, 0, 0, 0);
            #pragma unroll
            for (int r = 0; r < 16; ++r)
                cin1[r] = fmaf(xt, (float)wih_h[1][r], (float)bias_h[1][r]);
            f32x16 a1 = __builtin_amdgcn_mfma_f32_32x32x16_f16(afrag[1], bfrag[rb], cin1, 0, 0, 0);

            float dh[8], nh[8], h[8];
            #pragma unroll
            for (int u = 0; u < 8; ++u) {
                const float ea = __builtin_amdgcn_exp2f(a0[u]);      // e^{-gi}
                const float ef = __builtin_amdgcn_exp2f(a0[u + 8]);  // e^{-gf}
                const float eb = __builtin_amdgcn_exp2f(a1[u]);      // e^{2gg}
                const float eo = __builtin_amdgcn_exp2f(a1[u + 8]);  // e^{-go}
                const float pf   = 1.0f + ef;
                const float pa   = 1.0f + ea;
                const float den1 = fmaf(pa, eb, pa);                  // (1+ea)(eb+1)
                const float D    = den1 * pf;
                const float rD   = __builtin_amdgcn_rcpf(D);
                const float num  = fmaf(eb, 2.0f * LOG2E, -2.0f * LOG2E);
                const float m1   = num * pf;
                const float cn   = fmaf(c[rb][u], den1, m1);
                const float cs   = cn * rD;
                c[rb][u] = cs;
                const float ec   = __builtin_amdgcn_exp2f(cs);        // e^{2c}
                const float ph   = 1.0f + eo;
                dh[u] = fmaf(ph, ec, ph);                             // (1+eo)(ec+1)
                nh[u] = ec - 1.0f;
            }
            #pragma unroll
            for (int u = 0; u < 8; u += 2) {
                const float P  = dh[u] * dh[u + 1];
                const float rP = __builtin_amdgcn_rcpf(P);
                h[u]     = (nh[u]     * dh[u + 1]) * rP;
                h[u + 1] = (nh[u + 1] * dh[u])     * rP;
            }
            unsigned q0 = pk16(h[0], h[1]);
            unsigned q1 = pk16(h[2], h[3]);
            unsigned q2 = pk16(h[4], h[5]);
            unsigned q3 = pk16(h[6], h[7]);
            auto s02 = __builtin_amdgcn_permlane32_swap(q0, q2, false, false);
            auto s13 = __builtin_amdgcn_permlane32_swap(q1, q3, false, false);
            u32x4 bw = { s02[0], s13[0], s02[1], s13[1] };
            bfrag[rb] = __builtin_bit_cast(f16x8, bw);
        }
    }

    // ---- final h straight from bfrag (B layout: lane holds units hi*8+e of col) ----
    #pragma unroll
    for (int rb = 0; rb < 2; ++rb) {
        const int rr = wib * 64 + col + rb * 32;
        #pragma unroll
        for (int e = 0; e < 8; ++e)
            hbuf[rr][hi * 8 + e] = (float)bfrag[rb][e];
    }
    __syncthreads();

    // ---- fc stage: thread tid owns block-local row tid ----
    const int grow = blockRow0 + tid;

    float x19[19];
    #pragma unroll
    for (int k = 0; k < 16; ++k) x19[k] = hbuf[tid][k];

    float ctl[5];
    #pragma unroll
    for (int k = 0; k < 5; ++k) ctl[k] = controls[grow * 5 + k];
    #pragma unroll
    for (int j = 0; j < 3; ++j) {
        float a = b_cc[j];
        #pragma unroll
        for (int k = 0; k < 5; ++k) a = fmaf(ctl[k], W_cc[j * 5 + k], a);
        x19[16 + j] = a;
    }

    // fc1: Linear(19->16); tanh via pairwise-merged rcp
    float d1[16];
    #pragma unroll
    for (int j = 0; j < 16; ++j) {
        float a = b1[j];
        #pragma unroll
        for (int k = 0; k < 19; ++k) a = fmaf(x19[k], W1[j * 19 + k], a);
        d1[j] = __builtin_amdgcn_exp2f((2.0f * LOG2E) * a) + 1.0f;
    }
    v2f t12[8];
    #pragma unroll
    for (int j = 0; j < 16; j += 2) {
        const float rP = __builtin_amdgcn_rcpf(d1[j] * d1[j + 1]);
        t12[j >> 1][0] = fmaf(-2.0f * d1[j + 1], rP, 1.0f);
        t12[j >> 1][1] = fmaf(-2.0f * d1[j],     rP, 1.0f);
    }

    // fc2: Linear(16->16) + tanh (packed fma, pairwise-merged rcp)
    float d2[16];
    #pragma unroll
    for (int j = 0; j < 16; ++j) {
        const v2f* w2row = (const v2f*)(W2 + j * 16);
        v2f a = t12[0] * w2row[0];
        #pragma unroll
        for (int p = 1; p < 8; ++p) a = __builtin_elementwise_fma(t12[p], w2row[p], a);
        d2[j] = __builtin_amdgcn_exp2f((2.0f * LOG2E) * (a.x + a.y + b2[j])) + 1.0f;
    }
    v2f t22[8];
    #pragma unroll
    for (int j = 0; j < 16; j += 2) {
        const float rP = __builtin_amdgcn_rcpf(d2[j] * d2[j + 1]);
        t22[j >> 1][0] = fmaf(-2.0f * d2[j + 1], rP, 1.0f);
        t22[j >> 1][1] = fmaf(-2.0f * d2[j],     rP, 1.0f);
    }

    // fc3: Linear(16->1) + ReLU
    const v2f* w3p = (const v2f*)W3;
    v2f a3 = t22[0] * w3p[0];
    #pragma unroll
    for (int p = 1; p < 8; ++p) a3 = __builtin_elementwise_fma(t22[p], w3p[p], a3);
    const float r = a3.x + a3.y + b3[0];
    if (grow < Btot) out[grow] = fmaxf(r, 0.0f);
}

extern "C" void kernel_launch(void* const* d_in, const int* in_sizes, int n_in,
                              void* d_out, int out_size, void* d_ws, size_t ws_size,
                              hipStream_t stream) {
    const float* mobility = (const float*)d_in[0];
    const float* controls = (const float*)d_in[1];
    // d_in[2] = last : unused by the reference
    const float* W_cc = (const float*)d_in[3];
    const float* b_cc = (const float*)d_in[4];
    const float* W_ih = (const float*)d_in[5];
    const float* W_hh = (const float*)d_in[6];
    const float* b_ih = (const float*)d_in[7];
    const float* b_hh = (const float*)d_in[8];
    const float* W1   = (const float*)d_in[9];
    const float* b1   = (const float*)d_in[10];
    const float* W2   = (const float*)d_in[11];
    const float* b2   = (const float*)d_in[12];
    const float* W3   = (const float*)d_in[13];
    const float* b3   = (const float*)d_in[14];
    float* out = (float*)d_out;

    const int Btot = in_sizes[0] / 7;          // 1048576
    const int grid = (Btot + 255) / 256;       // 256 rows per block (4 waves x 64)

    lstm_mfma_kernel<<<grid, 256, 0, stream>>>(
        mobility, controls, W_cc, b_cc, W_ih, W_hh, b_ih, b_hh,
        W1, b1, W2, b2, W3, b3, out, Btot);
}